// Round 1
// baseline (696.356 us; speedup 1.0000x reference)
//
#include <hip/hip_runtime.h>
#include <hip/hip_bf16.h>

// Problem constants (also derivable from in_sizes, done in kernel_launch):
//   N = 50000 nodes, E = 1.6M edges, D = 16, NK = 2
// Pipeline:
//   h1[N,32]  = aniso_conv(x[N,16])          (scatter-add by dst, kernel-major)
//   h1        = l2norm(relu(h1 @ W1 + b1))   (in-place)
//   h2[N,64]  = aniso_conv(h1)
//   out[N,64] = l2norm((relu(h2@W2a+b2a))@W2b + b2b)

#define EPSV 1e-12f

// ---- detect whether edge_index buffer is int64 (odd int32 words all zero) ----
__global__ void detect_i64_kernel(const int* ei, int* flag) {
    int lane = threadIdx.x;
    int nonzero = 0;
    for (int i = lane; i < 1024; i += 64) {
        if (ei[2 * i + 1] != 0) nonzero = 1;
    }
    unsigned long long b = __ballot(nonzero);
    if (lane == 0) *flag = (b == 0ull) ? 1 : 0;   // 1 => int64 layout
}

__device__ __forceinline__ void load_edge(const int* ei, int e, int E, int flag,
                                          int& src, int& dst) {
    if (flag) {            // int64 storage: low words at even int32 indices
        src = ei[2 * e];
        dst = ei[2 * E + 2 * e];
    } else {               // int32 storage
        src = ei[e];
        dst = ei[E + e];
    }
}

// ---- conv1: x[N,16] -> h1[N,32], 16 lanes per edge ----
__global__ void conv1_kernel(const float* __restrict__ x,
                             const float* __restrict__ K,
                             const int* __restrict__ ei,
                             const int* __restrict__ flagp,
                             float* __restrict__ h1, int E) {
    int tid = blockIdx.x * 256 + threadIdx.x;
    int e = tid >> 4;
    int c = tid & 15;
    if (e >= E) return;
    int flag = *flagp;
    int src, dst;
    load_edge(ei, e, E, flag, src, dst);
    float k0 = K[e];
    float k1 = K[E + e];
    float xv = x[src * 16 + c];
    atomicAdd(&h1[dst * 32 + c], k0 * xv);
    atomicAdd(&h1[dst * 32 + 16 + c], k1 * xv);
}

// ---- conv2: h1[N,32] -> h2[N,64], 32 lanes per edge ----
__global__ void conv2_kernel(const float* __restrict__ h1,
                             const float* __restrict__ K,
                             const int* __restrict__ ei,
                             const int* __restrict__ flagp,
                             float* __restrict__ h2, int E) {
    int tid = blockIdx.x * 256 + threadIdx.x;
    int e = tid >> 5;
    int c = tid & 31;
    if (e >= E) return;
    int flag = *flagp;
    int src, dst;
    load_edge(ei, e, E, flag, src, dst);
    float k0 = K[e];
    float k1 = K[E + e];
    float v = h1[src * 32 + c];
    atomicAdd(&h2[dst * 64 + c], k0 * v);
    atomicAdd(&h2[dst * 64 + 32 + c], k1 * v);
}

// ---- MLP1: h1 = l2norm(relu(h1 @ W1[32,32] + b1)), in place. 32 lanes/node ----
__global__ void mlp1_kernel(float* __restrict__ h1,
                            const float* __restrict__ W1,
                            const float* __restrict__ b1, int N) {
    __shared__ float w[32 * 32];
    __shared__ float b[32];
    for (int i = threadIdx.x; i < 1024; i += 256) w[i] = W1[i];
    if (threadIdx.x < 32) b[threadIdx.x] = b1[threadIdx.x];
    __syncthreads();
    int g = threadIdx.x >> 5;
    int lane = threadIdx.x & 31;
    int node = blockIdx.x * 8 + g;
    if (node >= N) return;
    float v = h1[node * 32 + lane];
    float acc = b[lane];
#pragma unroll
    for (int i = 0; i < 32; i++) acc += __shfl(v, i, 32) * w[i * 32 + lane];
    acc = fmaxf(acc, 0.0f);
    float ss = acc * acc;
#pragma unroll
    for (int m = 16; m >= 1; m >>= 1) ss += __shfl_xor(ss, m, 32);
    float nrm = sqrtf(ss);
    h1[node * 32 + lane] = acc / fmaxf(nrm, EPSV);
}

// ---- MLP2: out = l2norm(relu(h2@W2a+b2a)@W2b + b2b). 64 lanes/node ----
__global__ void mlp2_kernel(const float* __restrict__ h2,
                            const float* __restrict__ W2a,
                            const float* __restrict__ b2a,
                            const float* __restrict__ W2b,
                            const float* __restrict__ b2b,
                            float* __restrict__ out, int N) {
    __shared__ float wa[64 * 128];
    __shared__ float wb[128 * 64];
    __shared__ float ba[128];
    __shared__ float bb[64];
    for (int i = threadIdx.x; i < 8192; i += 256) {
        wa[i] = W2a[i];
        wb[i] = W2b[i];
    }
    if (threadIdx.x < 128) ba[threadIdx.x] = b2a[threadIdx.x];
    if (threadIdx.x < 64) bb[threadIdx.x] = b2b[threadIdx.x];
    __syncthreads();
    int w = threadIdx.x >> 6;
    int lane = threadIdx.x & 63;
    int node = blockIdx.x * 4 + w;
    if (node >= N) return;
    float v = h2[node * 64 + lane];
    float hA = ba[lane];
    float hB = ba[lane + 64];
#pragma unroll
    for (int i = 0; i < 64; i++) {
        float xi = __shfl(v, i, 64);
        hA += xi * wa[i * 128 + lane];
        hB += xi * wa[i * 128 + 64 + lane];
    }
    hA = fmaxf(hA, 0.0f);
    hB = fmaxf(hB, 0.0f);
    float o = bb[lane];
#pragma unroll
    for (int j = 0; j < 64; j++) {
        o += __shfl(hA, j, 64) * wb[j * 64 + lane];
        o += __shfl(hB, j, 64) * wb[(64 + j) * 64 + lane];
    }
    float ss = o * o;
#pragma unroll
    for (int m = 32; m >= 1; m >>= 1) ss += __shfl_xor(ss, m, 64);
    float nrm = sqrtf(ss);
    out[node * 64 + lane] = o / fmaxf(nrm, EPSV);
}

extern "C" void kernel_launch(void* const* d_in, const int* in_sizes, int n_in,
                              void* d_out, int out_size, void* d_ws, size_t ws_size,
                              hipStream_t stream) {
    const float* x   = (const float*)d_in[0];
    const float* K   = (const float*)d_in[1];
    const int*   ei  = (const int*)d_in[2];
    const float* W1  = (const float*)d_in[3];
    const float* b1  = (const float*)d_in[4];
    const float* W2a = (const float*)d_in[5];
    const float* b2a = (const float*)d_in[6];
    const float* W2b = (const float*)d_in[7];
    const float* b2b = (const float*)d_in[8];
    float* out = (float*)d_out;

    const int D  = 16;
    const int NK = 2;
    const int N  = in_sizes[0] / D;        // 50000
    const int E  = in_sizes[1] / NK;       // 1600000

    // workspace layout (floats): h1[N*32] | h2[N*64] | flag(int)
    float* h1 = (float*)d_ws;
    float* h2 = h1 + (size_t)N * 32;
    int* flag = (int*)(h2 + (size_t)N * 64);

    // zero the accumulation buffers (required every call)
    hipMemsetAsync(d_ws, 0, (size_t)N * 96 * sizeof(float), stream);

    detect_i64_kernel<<<1, 64, 0, stream>>>(ei, flag);

    {
        int total = E * 16;
        int blocks = (total + 255) / 256;
        conv1_kernel<<<blocks, 256, 0, stream>>>(x, K, ei, flag, h1, E);
    }
    {
        int blocks = (N + 7) / 8;
        mlp1_kernel<<<blocks, 256, 0, stream>>>(h1, W1, b1, N);
    }
    {
        long long total = (long long)E * 32;
        int blocks = (int)((total + 255) / 256);
        conv2_kernel<<<blocks, 256, 0, stream>>>(h1, K, ei, flag, h2, E);
    }
    {
        int blocks = (N + 3) / 4;
        mlp2_kernel<<<blocks, 256, 0, stream>>>(h2, W2a, b2a, W2b, b2b, out, N);
    }
}